// Round 13
// baseline (143.806 us; speedup 1.0000x reference)
//
#include <hip/hip_runtime.h>
#include <cmath>

#define E_ 4
#define L_ 10
#define M_ 512
#define F_ 128
#define S_ 1000

typedef unsigned int u32;
typedef _Float16 f16;
typedef __attribute__((ext_vector_type(8))) _Float16 v8h;
typedef __attribute__((ext_vector_type(4))) float v4f;

__device__ __forceinline__ float fexp2(float a){
#if __has_builtin(__builtin_amdgcn_exp2f)
  return __builtin_amdgcn_exp2f(a);
#else
  return exp2f(a);
#endif
}

// ws float layout:
// [0..4)         splat consts: posScale, posOff, stepFS, leftS (written by k_red)
// [8]            hscale (written by k_red, read by k_fin)
// [16..1296)     per-gemm-block min (live k_pre -> k_red; reused by k_nul probe
//                as dead scratch afterwards)
// [1296..2576)   per-gemm-block max
// [2576..7696)   std S1 partials [40][128]
// [7696..12816)  std S2 partials [40][128]
// [12816..20496) dpair[6][1280]
// [20496..282640) projT[E][L][F][M] (unscaled, m contiguous)
//
// R13: DIFFERENTIAL FLOOR PROBE. Everything is byte-identical R11 (best,
// 141.4us). k_nul = k_kde's shell (same grid, same 23.9KB LDS, same projT
// loads, 2 barriers, 1 live store) with zero interior work. total - 141.4
// = k_nul + one gap -> measures the structural floor of the k_kde dispatch.
// Readout pre-committed: >=35us -> interior near-optimal, declare ceiling;
// <=15us -> 40us of interior cost is real, attack FIR/splat next.

// blocks 0..1279: MFMA f16 GEMM tile (direct global loads/stores) + block min/max
// blocks 1280..1319: per-(e,l) std partial sums (float4 loads, 8 parts x 64 iters)
__global__ __launch_bounds__(256) void k_pre(const float* __restrict__ mat,
                       const float* __restrict__ par,
                       float* __restrict__ projT, float* __restrict__ wsf){
  __shared__ float sm[2048];
  int b = blockIdx.x, tid = threadIdx.x;
  if (b >= 1280){
    int el = b - 1280;
    int fq = (tid & 31) * 4, part = tid >> 5;     // 8 parts x 64 samples
    const float* base = mat + ((size_t)el * M_ + part*64) * F_;
    float4 s  = make_float4(0.f,0.f,0.f,0.f);
    float4 s2 = make_float4(0.f,0.f,0.f,0.f);
    #pragma unroll 8
    for (int i = 0; i < 64; i++){
      float4 v = *(const float4*)&base[i*F_ + fq];
      s.x += v.x; s.y += v.y; s.z += v.z; s.w += v.w;
      s2.x += v.x*v.x; s2.y += v.y*v.y; s2.z += v.z*v.z; s2.w += v.w*v.w;
    }
    ((float4*)sm)[tid]       = s;
    ((float4*)sm)[256 + tid] = s2;
    __syncthreads();
    for (int g = 4; g >= 1; g >>= 1){
      if (part < g){
        float4 o  = ((float4*)sm)[tid + g*32];
        float4 o2 = ((float4*)sm)[256 + tid + g*32];
        s.x += o.x; s.y += o.y; s.z += o.z; s.w += o.w;
        s2.x += o2.x; s2.y += o2.y; s2.z += o2.z; s2.w += o2.w;
        ((float4*)sm)[tid] = s;
        ((float4*)sm)[256 + tid] = s2;
      }
      __syncthreads();
    }
    if (part == 0){
      *(float4*)&wsf[2576 + el*128 + fq] = s;
      *(float4*)&wsf[7696 + el*128 + fq] = s2;
    }
    return;
  }
  int el = b >> 5, mt = (b & 31) * 16;
  int lane = tid & 63, wave = tid >> 6;
  int q = (lane >> 4) & 3, m16 = lane & 15;
  const float* arow = mat + ((size_t)el * M_ + mt + m16) * F_;
  v4f acc0 = {0.f,0.f,0.f,0.f}, acc1 = {0.f,0.f,0.f,0.f};
  #pragma unroll
  for (int c = 0; c < 4; c++){
    float4 a0 = *(const float4*)&arow[c*32 + q*8];
    float4 a1 = *(const float4*)&arow[c*32 + q*8 + 4];
    v8h af, b0, b1;
    af[0]=(f16)a0.x; af[1]=(f16)a0.y; af[2]=(f16)a0.z; af[3]=(f16)a0.w;
    af[4]=(f16)a1.x; af[5]=(f16)a1.y; af[6]=(f16)a1.z; af[7]=(f16)a1.w;
    const float* pb = par + (c*32 + q*8)*F_ + wave*32 + m16;
    #pragma unroll
    for (int j = 0; j < 8; j++){
      b0[j] = (f16)pb[j*F_];
      b1[j] = (f16)pb[j*F_ + 16];
    }
    acc0 = __builtin_amdgcn_mfma_f32_16x16x32_f16(af, b0, acc0, 0, 0, 0);
    acc1 = __builtin_amdgcn_mfma_f32_16x16x32_f16(af, b1, acc1, 0, 0, 0);
  }
  // direct stores: C/D row=q*4+r (m), col=m16 (n) -> projT[el][n][m]
  *(float4*)(projT + ((size_t)el*F_ + wave*32      + m16)*M_ + mt + q*4)
      = make_float4(acc0[0], acc0[1], acc0[2], acc0[3]);
  *(float4*)(projT + ((size_t)el*F_ + wave*32 + 16 + m16)*M_ + mt + q*4)
      = make_float4(acc1[0], acc1[1], acc1[2], acc1[3]);
  float lmin =  3.4e38f, lmax = -3.4e38f;
  #pragma unroll
  for (int r = 0; r < 4; r++){
    lmin = fminf(lmin, fminf(acc0[r], acc1[r]));
    lmax = fmaxf(lmax, fmaxf(acc0[r], acc1[r]));
  }
  #pragma unroll
  for (int d = 32; d >= 1; d >>= 1){
    lmin = fminf(lmin, __shfl_xor(lmin, d, 64));
    lmax = fmaxf(lmax, __shfl_xor(lmax, d, 64));
  }
  if (lane == 0){ sm[wave] = lmin; sm[8+wave] = lmax; }
  __syncthreads();
  if (tid == 0){
    wsf[16   + b] = fminf(fminf(sm[0], sm[1]), fminf(sm[2], sm[3]));
    wsf[1296 + b] = fmaxf(fmaxf(sm[8], sm[9]), fmaxf(sm[10], sm[11]));
  }
}

// one-block reduction: global min/max + std-sum -> splat constants + hscale.
__global__ __launch_bounds__(1024) void k_red(float* __restrict__ wsf,
                                              float divisor){
  __shared__ float rmn[1024], rmx[1024], rs[1024];
  int tid = threadIdx.x;
  float mn = 3.4e38f, mx = -3.4e38f, s = 0.f;
  for (int i = tid; i < 1280; i += 1024){
    mn = fminf(mn, wsf[16   + i]);
    mx = fmaxf(mx, wsf[1296 + i]);
  }
  for (int i = tid; i < 5120; i += 1024){
    float a  = wsf[2576 + i];
    float a2 = wsf[7696 + i];
    float mean = a * (1.0f/512.0f);
    float var  = a2 * (1.0f/512.0f) - mean*mean;
    s += sqrtf(fmaxf(var, 0.0f));
  }
  rmn[tid] = mn; rmx[tid] = mx; rs[tid] = s;
  __syncthreads();
  for (int g = 512; g >= 1; g >>= 1){
    if (tid < g){
      rmn[tid] = fminf(rmn[tid], rmn[tid+g]);
      rmx[tid] = fmaxf(rmx[tid], rmx[tid+g]);
      rs[tid] += rs[tid+g];
    }
    __syncthreads();
  }
  if (tid == 0){
    float rstd   = 5120.0f / rs[0];
    float leftS  = rmn[0] * rstd;
    float rightS = rmx[0] * rstd;
    float stepFS = (rightS - leftS) * (1.0f/999.0f);
    float inv2   = 1.0f / (2.0f * stepFS);
    wsf[0] = rstd * inv2;    // posScale
    wsf[1] = leftS * inv2;   // posOff
    wsf[2] = stepFS;
    wsf[3] = leftS;
    wsf[8] = ((rightS - leftS) * (1.0f/1000.0f)) * 0.5f / divisor;  // hscale
  }
}

// NULL PROBE: k_kde's shell with zero interior work. Same grid (1280x256),
// same LDS footprint (5976 floats), same projT/const/dlen loads (kept live
// via data-dependent store), 2 barriers, 1 store to dead scratch.
__global__ __launch_bounds__(256) void k_nul(const float* __restrict__ projT,
                      const int* __restrict__ dlen, const float* __restrict__ wsf,
                      float* __restrict__ scratch){
  __shared__ __align__(16) float smem[5976];
  int b = blockIdx.x;
  int l = b >> 7, f = b & 127;
  int tid = threadIdx.x, wave = tid >> 6, lane = tid & 63;
  int e = wave;
  const float4* gp = (const float4*)(projT + (((size_t)e * L_ + l) * F_ + f) * M_);
  float4 g0 = gp[lane], g1 = gp[lane + 64];
  float posScale = wsf[0], posOff = wsf[1];
  float lenE = (float)dlen[e*L_ + l];
  // keep all loads alive + force LDS allocation (data-dependent store)
  smem[tid] = g0.x + g0.w + g1.x + g1.w + posScale + posOff + lenE;
  __syncthreads();                       // barrier #1 (mirrors k_kde)
  float v = smem[(tid + 128) & 255];
  __syncthreads();                       // barrier #2
  if (tid == 0) scratch[b] = v;          // dead slot: wsf[16..1296)
}

// KDE: 256 threads, wave = env, FULLY WAVE-PRIVATE until the pairwise phase
// (byte-identical R11).
// smem: st [0..1024) | hist 4x824 [1024..4320) | taps 4x152 [4320..4928) |
//       corr 4x256 [4928..5952) | partials [5952..5976)
__global__ __launch_bounds__(256) void k_kde(const float* __restrict__ projT,
                      const int* __restrict__ dlen, const float* __restrict__ wsf,
                      float* __restrict__ dpair, float k2c){
  __shared__ __align__(16) float smem[5976];
  int b = blockIdx.x;          // 0..1279
  int l = b >> 7, f = b & 127;
  int tid = threadIdx.x, wave = tid >> 6, lane = tid & 63;
  int e = wave;
  // long-latency loads issued first
  const float4* gp = (const float4*)(projT + (((size_t)e * L_ + l) * F_ + f) * M_);
  float4 g0 = gp[lane], g1 = gp[lane + 64];
  float posScale = wsf[0], posOff = wsf[1], stepFS = wsf[2], leftS = wsf[3];
  float lenE = (float)dlen[e*L_ + l];
  float sh = 2.0f * stepFS;
  // ---- wave-private phase (no barriers) ----
  // zero own padded hist (824 floats = 206 float4)
  {
    float4* hz = (float4*)(smem + 1024 + e*824);
    #pragma unroll
    for (int i = 0; i < 4; i++){
      int idx = lane + i*64;
      if (idx < 206) hz[idx] = make_float4(0.f,0.f,0.f,0.f);
    }
  }
  // build own tap table (152 floats; [0..7] zero-pad, pair p at [8+2p..])
  {
    float* tw = smem + 4320 + e*152;
    #pragma unroll
    for (int i = 0; i < 3; i++){
      int t = lane + i*64;
      if (t < 152){
        float v = 0.f;
        if (t >= 8){
          int pr = (t >> 1) - 4;       // pair index 0..71
          int u  = pr - 34;
          float d = (t & 1) ? (float)(2*u-1) * sh : (float)(2*u) * sh;
          v = (pr < 69) ? fexp2(k2c*d*d) : 0.f;
        }
        tw[t] = v;
      }
    }
  }
  // build own corr table (256 floats)
  {
    float* cw = smem + 4928 + e*256;
    #pragma unroll
    for (int i = 0; i < 4; i++){
      int t = lane + i*64;
      float xc = fmaf((float)(t - 1), 4.0f*stepFS, leftS);
      cw[t] = fexp2(k2c * xc * xc);
    }
  }
  // quadratic (TSC) splat into own padded histogram
  {
    float* hf = smem + 1024 + e*824;
    float pv[8] = {g0.x,g0.y,g0.z,g0.w,g1.x,g1.y,g1.z,g1.w};
    #pragma unroll
    for (int i = 0; i < 8; i++){
      float pos = fmaf(pv[i], posScale, -posOff);
      float n = floorf(pos + 0.5f);
      float d = pos - n;
      float wm = 0.5f*(0.5f-d)*(0.5f-d);
      float wp = 0.5f*(0.5f+d)*(0.5f+d);
      float w0 = 0.75f - d*d;
      int b0 = (int)n + 71;
      int b1 = b0 + 1, b2 = b0 + 2;
      int W0 = b0 + ((b0>>3)<<1);
      int W1 = b1 + ((b1>>3)<<1);
      int W2 = b2 + ((b2>>3)<<1);
      atomicAdd(&hf[W0], wm);
      atomicAdd(&hf[W1], w0);
      atomicAdd(&hf[W2], wp);
    }
  }
  // same-wave DS FIFO: atomics above complete before the reads below; drain
  // outstanding returns to be safe.
  asm volatile("s_waitcnt lgkmcnt(0)");
  __builtin_amdgcn_sched_barrier(0);
  // FIR: lane computes 4 consecutive outputs o = 4*lane + r of env e
  float rlen = 1.0f / lenE;
  float padc = 512.0f - lenE;
  {
    const float2* sK2 = (const float2*)(smem + 4320 + e*152);
    const float* hl = smem + 1024 + e*824 + 10*lane;
    float2 c0 = sK2[72], c1 = sK2[73], c2 = sK2[74], c3 = sK2[75];
    float a0=0.f, a1=0.f, a2=0.f, a3=0.f;
    #pragma unroll
    for (int g = 0; g < 9; g++){
      float2 Hb[8];
      #pragma unroll
      for (int j = 0; j < 8; j++){
        int i = g*8 + j + 1;                 // 1..72
        Hb[j] = *(const float2*)&hl[2*i + 2*(i>>2)];
      }
      __builtin_amdgcn_sched_group_barrier(0x100, 8, 0);  // cluster the 8 reads
      #pragma unroll
      for (int j = 0; j < 8; j++){
        int i = g*8 + j + 1;
        a0 = fmaf(Hb[j].x, c0.x, fmaf(Hb[j].y, c0.y, a0));
        a1 = fmaf(Hb[j].x, c1.x, fmaf(Hb[j].y, c1.y, a1));
        a2 = fmaf(Hb[j].x, c2.x, fmaf(Hb[j].y, c2.y, a2));
        a3 = fmaf(Hb[j].x, c3.x, fmaf(Hb[j].y, c3.y, a3));
        c3 = c2; c2 = c1; c1 = c0; c0 = sK2[72 - i];
      }
    }
    int o0 = 4*lane;
    float4 cr = *(const float4*)&smem[4928 + e*256 + o0];
    float4 stv = make_float4((a0 - padc*cr.x)*rlen, (a1 - padc*cr.y)*rlen,
                             (a2 - padc*cr.z)*rlen, (a3 - padc*cr.w)*rlen);
    *(float4*)&smem[e*256 + o0] = stv;
  }
  __syncthreads();   // #1 (of 2): all envs' st complete
  // fine grid: thread tid handles t = 4*tid..4*tid+3 (all share cc = tid)
  float ps[6] = {0,0,0,0,0,0};
  if (tid < 250){
    float x[4][4];
    #pragma unroll
    for (int ee=0; ee<4; ee++){
      const float* st = &smem[ee*256 + tid];
      x[ee][0]=st[0]; x[ee][1]=st[1]; x[ee][2]=st[2]; x[ee][3]=st[3];
    }
    __builtin_amdgcn_sched_group_barrier(0x100, 16, 0);   // cluster the 16 reads
    #pragma unroll
    for (int k=0; k<4; k++){
      float u = (float)k * 0.25f;
      float um1 = u - 1.0f, um2 = u - 2.0f, up1 = u + 1.0f;
      float w0 = -u * um1 * um2 * (1.0f/6.0f);
      float w1 = up1 * um1 * um2 * 0.5f;
      float w2 = -u * up1 * um2 * 0.5f;
      float w3 = u * up1 * um1 * (1.0f/6.0f);
      float rr[4];
      #pragma unroll
      for (int ee=0; ee<4; ee++)
        rr[ee] = w0*x[ee][0] + w1*x[ee][1] + w2*x[ee][2] + w3*x[ee][3];
      ps[0] += fabsf(rr[0]-rr[1]);
      ps[1] += fabsf(rr[0]-rr[2]);
      ps[2] += fabsf(rr[0]-rr[3]);
      ps[3] += fabsf(rr[1]-rr[2]);
      ps[4] += fabsf(rr[1]-rr[3]);
      ps[5] += fabsf(rr[2]-rr[3]);
    }
  }
  #pragma unroll
  for (int pr=0; pr<6; pr++){
    float v = ps[pr];
    #pragma unroll
    for (int d=32; d>=1; d>>=1) v += __shfl_xor(v, d, 64);
    if (lane == 0) smem[5952 + wave*6 + pr] = v;
  }
  __syncthreads();   // #2 (of 2): partials visible
  if (tid < 6)
    dpair[tid*1280 + b] = smem[5952+tid] + smem[5958+tid] + smem[5964+tid] + smem[5970+tid];
}

// finalize: scale, masked max over pairs, then max over L + mean over F
__global__ void k_fin(const float* __restrict__ dpair, const float* __restrict__ wsf,
                      const int* __restrict__ istrain, float* __restrict__ out){
  __shared__ float str[1280], ste[1280];
  __shared__ float s1[128], s2[128];
  int tid = threadIdx.x;   // 256 threads, 1 block
  float hscale = wsf[8];
  bool t0 = istrain[0]!=0, t1 = istrain[1]!=0, t2 = istrain[2]!=0, t3 = istrain[3]!=0;
  bool trn[6] = { t0&&t1, t0&&t2, t0&&t3, t1&&t2, t1&&t3, t2&&t3 };
  for (int idx = tid; idx < 1280; idx += 256){
    float tmax = -INFINITY, trmax = -INFINITY;
    #pragma unroll
    for (int pr=0;pr<6;pr++){
      float h = dpair[pr*1280 + idx] * hscale;
      tmax = fmaxf(tmax, h);
      if (trn[pr]) trmax = fmaxf(trmax, h);
    }
    out[idx]        = trmax;   // train_results
    out[1280 + idx] = tmax;    // test_results
    str[idx] = trmax; ste[idx] = tmax;
  }
  __syncthreads();
  if (tid < 128){
    float m1 = -INFINITY, m2 = -INFINITY;
    for (int l=0;l<L_;l++){
      m1 = fmaxf(m1, str[l*F_ + tid]);
      m2 = fmaxf(m2, ste[l*F_ + tid]);
    }
    s1[tid] = m1; s2[tid] = m2;
  }
  __syncthreads();
  for (int g=64; g>=1; g>>=1){
    if (tid < g){ s1[tid] += s1[tid+g]; s2[tid] += s2[tid+g]; }
    __syncthreads();
  }
  if (tid == 0){
    out[2560] = s1[0] * (1.0f/128.0f);
    out[2561] = s2[0] * (1.0f/128.0f);
  }
}

extern "C" void kernel_launch(void* const* d_in, const int* in_sizes, int n_in,
                              void* d_out, int out_size, void* d_ws, size_t ws_size,
                              hipStream_t stream){
  const float* mat = (const float*)d_in[0];
  const float* par = (const float*)d_in[1];
  const int*  dlen = (const int*)d_in[2];
  const int*  istr = (const int*)d_in[3];
  float* out   = (float*)d_out;
  float* wsf   = (float*)d_ws;
  float* dpair = wsf + 12816;
  float* projT = wsf + 20496;

  // host-computable constants (bw's data-dependent factor is identically 1)
  double bw_d   = 1.06 * pow(512.0, -0.2);
  float  bw     = (float)bw_d;
  float  offset = expf(-0.5f / (bw*bw));
  float  k2c    = (float)(log((double)offset) * 1.4426950408889634);  // log2(offset)
  float  divisor = sqrtf(6.283185307179586f) * bw;

  k_pre <<<1320, 256, 0, stream>>>(mat, par, projT, wsf);
  k_red <<<1,   1024, 0, stream>>>(wsf, divisor);
  // FLOOR PROBE: k_kde's shell, zero interior (scratch = dead min-slot region)
  k_nul <<<1280, 256, 0, stream>>>(projT, dlen, wsf, wsf + 16);
  k_kde <<<1280, 256, 0, stream>>>(projT, dlen, wsf, dpair, k2c);
  k_fin <<<1,    256, 0, stream>>>(dpair, wsf, istr, out);
}

// Round 14
// 139.635 us; speedup vs baseline: 1.0299x; 1.0299x over previous
//
#include <hip/hip_runtime.h>
#include <cmath>

#define E_ 4
#define L_ 10
#define M_ 512
#define F_ 128
#define S_ 1000

typedef unsigned int u32;
typedef _Float16 f16;
typedef __attribute__((ext_vector_type(8))) _Float16 v8h;
typedef __attribute__((ext_vector_type(4))) float v4f;

__device__ __forceinline__ float fexp2(float a){
#if __has_builtin(__builtin_amdgcn_exp2f)
  return __builtin_amdgcn_exp2f(a);
#else
  return exp2f(a);
#endif
}

// ws float layout:
// [0..4)         splat consts: posScale, posOff, stepFS, leftS (written by k_red)
// [8]            hscale (written by k_red, read by k_fin)
// [16..1296)     per-gemm-block min   (live only k_pre -> k_red)
// [1296..2576)   per-gemm-block max
// [2576..7696)   std S1 partials [40][128]
// [7696..12816)  std S2 partials [40][128]
// [12816..20496) dpair[6][1280]
// [20496..282640) projT[E][L][F][M] (unscaled, m contiguous)
//
// R14: CUT DS INSTRUCTIONS 39%. R13 floor probe: k_kde shell = ~2.4us ->
// the 54us is interior. Occupancy-invariance (20-70%, R2/R12) = saturated
// shared pipe; by elimination the DS pipe (no busy counter exists for it).
// R3 (-17%, the only win) was the only round that cut DS instruction count.
// Here: 72 wave-uniform tap ds_read_b64 -> VALU (compile-time m, identical
// fexp2 expression -> bit-identical); corr table -> registers (R12-verified).
// DS instr/wave 203 -> 124. Splat/fine-grid/barriers byte-identical R11.

// blocks 0..1279: MFMA f16 GEMM tile (direct global loads/stores) + block min/max
// blocks 1280..1319: per-(e,l) std partial sums (float4 loads, 8 parts x 64 iters)
__global__ __launch_bounds__(256) void k_pre(const float* __restrict__ mat,
                       const float* __restrict__ par,
                       float* __restrict__ projT, float* __restrict__ wsf){
  __shared__ float sm[2048];
  int b = blockIdx.x, tid = threadIdx.x;
  if (b >= 1280){
    int el = b - 1280;
    int fq = (tid & 31) * 4, part = tid >> 5;     // 8 parts x 64 samples
    const float* base = mat + ((size_t)el * M_ + part*64) * F_;
    float4 s  = make_float4(0.f,0.f,0.f,0.f);
    float4 s2 = make_float4(0.f,0.f,0.f,0.f);
    #pragma unroll 8
    for (int i = 0; i < 64; i++){
      float4 v = *(const float4*)&base[i*F_ + fq];
      s.x += v.x; s.y += v.y; s.z += v.z; s.w += v.w;
      s2.x += v.x*v.x; s2.y += v.y*v.y; s2.z += v.z*v.z; s2.w += v.w*v.w;
    }
    ((float4*)sm)[tid]       = s;
    ((float4*)sm)[256 + tid] = s2;
    __syncthreads();
    for (int g = 4; g >= 1; g >>= 1){
      if (part < g){
        float4 o  = ((float4*)sm)[tid + g*32];
        float4 o2 = ((float4*)sm)[256 + tid + g*32];
        s.x += o.x; s.y += o.y; s.z += o.z; s.w += o.w;
        s2.x += o2.x; s2.y += o2.y; s2.z += o2.z; s2.w += o2.w;
        ((float4*)sm)[tid] = s;
        ((float4*)sm)[256 + tid] = s2;
      }
      __syncthreads();
    }
    if (part == 0){
      *(float4*)&wsf[2576 + el*128 + fq] = s;
      *(float4*)&wsf[7696 + el*128 + fq] = s2;
    }
    return;
  }
  int el = b >> 5, mt = (b & 31) * 16;
  int lane = tid & 63, wave = tid >> 6;
  int q = (lane >> 4) & 3, m16 = lane & 15;
  const float* arow = mat + ((size_t)el * M_ + mt + m16) * F_;
  v4f acc0 = {0.f,0.f,0.f,0.f}, acc1 = {0.f,0.f,0.f,0.f};
  #pragma unroll
  for (int c = 0; c < 4; c++){
    float4 a0 = *(const float4*)&arow[c*32 + q*8];
    float4 a1 = *(const float4*)&arow[c*32 + q*8 + 4];
    v8h af, b0, b1;
    af[0]=(f16)a0.x; af[1]=(f16)a0.y; af[2]=(f16)a0.z; af[3]=(f16)a0.w;
    af[4]=(f16)a1.x; af[5]=(f16)a1.y; af[6]=(f16)a1.z; af[7]=(f16)a1.w;
    const float* pb = par + (c*32 + q*8)*F_ + wave*32 + m16;
    #pragma unroll
    for (int j = 0; j < 8; j++){
      b0[j] = (f16)pb[j*F_];
      b1[j] = (f16)pb[j*F_ + 16];
    }
    acc0 = __builtin_amdgcn_mfma_f32_16x16x32_f16(af, b0, acc0, 0, 0, 0);
    acc1 = __builtin_amdgcn_mfma_f32_16x16x32_f16(af, b1, acc1, 0, 0, 0);
  }
  // direct stores: C/D row=q*4+r (m), col=m16 (n) -> projT[el][n][m]
  *(float4*)(projT + ((size_t)el*F_ + wave*32      + m16)*M_ + mt + q*4)
      = make_float4(acc0[0], acc0[1], acc0[2], acc0[3]);
  *(float4*)(projT + ((size_t)el*F_ + wave*32 + 16 + m16)*M_ + mt + q*4)
      = make_float4(acc1[0], acc1[1], acc1[2], acc1[3]);
  float lmin =  3.4e38f, lmax = -3.4e38f;
  #pragma unroll
  for (int r = 0; r < 4; r++){
    lmin = fminf(lmin, fminf(acc0[r], acc1[r]));
    lmax = fmaxf(lmax, fmaxf(acc0[r], acc1[r]));
  }
  #pragma unroll
  for (int d = 32; d >= 1; d >>= 1){
    lmin = fminf(lmin, __shfl_xor(lmin, d, 64));
    lmax = fmaxf(lmax, __shfl_xor(lmax, d, 64));
  }
  if (lane == 0){ sm[wave] = lmin; sm[8+wave] = lmax; }
  __syncthreads();
  if (tid == 0){
    wsf[16   + b] = fminf(fminf(sm[0], sm[1]), fminf(sm[2], sm[3]));
    wsf[1296 + b] = fmaxf(fmaxf(sm[8], sm[9]), fmaxf(sm[10], sm[11]));
  }
}

// one-block reduction: global min/max + std-sum -> splat constants + hscale.
__global__ __launch_bounds__(1024) void k_red(float* __restrict__ wsf,
                                              float divisor){
  __shared__ float rmn[1024], rmx[1024], rs[1024];
  int tid = threadIdx.x;
  float mn = 3.4e38f, mx = -3.4e38f, s = 0.f;
  for (int i = tid; i < 1280; i += 1024){
    mn = fminf(mn, wsf[16   + i]);
    mx = fmaxf(mx, wsf[1296 + i]);
  }
  for (int i = tid; i < 5120; i += 1024){
    float a  = wsf[2576 + i];
    float a2 = wsf[7696 + i];
    float mean = a * (1.0f/512.0f);
    float var  = a2 * (1.0f/512.0f) - mean*mean;
    s += sqrtf(fmaxf(var, 0.0f));
  }
  rmn[tid] = mn; rmx[tid] = mx; rs[tid] = s;
  __syncthreads();
  for (int g = 512; g >= 1; g >>= 1){
    if (tid < g){
      rmn[tid] = fminf(rmn[tid], rmn[tid+g]);
      rmx[tid] = fmaxf(rmx[tid], rmx[tid+g]);
      rs[tid] += rs[tid+g];
    }
    __syncthreads();
  }
  if (tid == 0){
    float rstd   = 5120.0f / rs[0];
    float leftS  = rmn[0] * rstd;
    float rightS = rmx[0] * rstd;
    float stepFS = (rightS - leftS) * (1.0f/999.0f);
    float inv2   = 1.0f / (2.0f * stepFS);
    wsf[0] = rstd * inv2;    // posScale
    wsf[1] = leftS * inv2;   // posOff
    wsf[2] = stepFS;
    wsf[3] = leftS;
    wsf[8] = ((rightS - leftS) * (1.0f/1000.0f)) * 0.5f / divisor;  // hscale
  }
}

// KDE: 256 threads, wave = env, wave-private until pairwise phase (R11),
// with taps computed in VALU (zero tap LDS traffic) and corr in registers.
// FIR iteration i consumes tap pair pr = 68-i: m0 = 68-2i, m1 = 67-2i
// (compile-time), value = fexp2(k2c*d*d), d = (float)m*sh — the IDENTICAL
// expression the old table build used -> bit-identical taps. Pairs with
// pr<0 (i>68) are compile-time zeros; initial c0 = pr=68, c1..c3 = 0.
// smem: st [0..1024) | hist 4x824 [1024..4320) | partials [4320..4344)
__global__ __launch_bounds__(256) void k_kde(const float* __restrict__ projT,
                      const int* __restrict__ dlen, const float* __restrict__ wsf,
                      float* __restrict__ dpair, float k2c){
  __shared__ __align__(16) float smem[4344];
  int b = blockIdx.x;          // 0..1279
  int l = b >> 7, f = b & 127;
  int tid = threadIdx.x, wave = tid >> 6, lane = tid & 63;
  int e = wave;
  // long-latency loads issued first
  const float4* gp = (const float4*)(projT + (((size_t)e * L_ + l) * F_ + f) * M_);
  float4 g0 = gp[lane], g1 = gp[lane + 64];
  float posScale = wsf[0], posOff = wsf[1], stepFS = wsf[2], leftS = wsf[3];
  float lenE = (float)dlen[e*L_ + l];
  float sh = 2.0f * stepFS;
  // ---- wave-private phase (no barriers) ----
  // zero own padded hist (824 floats = 206 float4)
  {
    float4* hz = (float4*)(smem + 1024 + e*824);
    #pragma unroll
    for (int i = 0; i < 4; i++){
      int idx = lane + i*64;
      if (idx < 206) hz[idx] = make_float4(0.f,0.f,0.f,0.f);
    }
  }
  // quadratic (TSC) splat into own padded histogram
  {
    float* hf = smem + 1024 + e*824;
    float pv[8] = {g0.x,g0.y,g0.z,g0.w,g1.x,g1.y,g1.z,g1.w};
    #pragma unroll
    for (int i = 0; i < 8; i++){
      float pos = fmaf(pv[i], posScale, -posOff);
      float n = floorf(pos + 0.5f);
      float d = pos - n;
      float wm = 0.5f*(0.5f-d)*(0.5f-d);
      float wp = 0.5f*(0.5f+d)*(0.5f+d);
      float w0 = 0.75f - d*d;
      int b0 = (int)n + 71;
      int b1 = b0 + 1, b2 = b0 + 2;
      int W0 = b0 + ((b0>>3)<<1);
      int W1 = b1 + ((b1>>3)<<1);
      int W2 = b2 + ((b2>>3)<<1);
      atomicAdd(&hf[W0], wm);
      atomicAdd(&hf[W1], w0);
      atomicAdd(&hf[W2], wp);
    }
  }
  // same-wave DS FIFO: atomics above complete before the reads below
  asm volatile("s_waitcnt lgkmcnt(0)");
  __builtin_amdgcn_sched_barrier(0);
  // FIR: lane computes 4 consecutive outputs o = 4*lane + r of env e.
  // H loads from LDS; taps computed in VALU per iteration.
  float rlen = 1.0f / lenE;
  float padc = 512.0f - lenE;
  {
    const float* hl = smem + 1024 + e*824 + 10*lane;
    float2 c0, c1 = make_float2(0.f,0.f), c2 = make_float2(0.f,0.f),
           c3 = make_float2(0.f,0.f);
    { // initial c0 = pair pr=68 (u=34): m0=68, m1=67
      float d0 = 68.0f * sh, d1 = 67.0f * sh;
      c0 = make_float2(fexp2(k2c*d0*d0), fexp2(k2c*d1*d1));
    }
    float a0=0.f, a1=0.f, a2=0.f, a3=0.f;
    #pragma unroll
    for (int g = 0; g < 9; g++){
      float2 Hb[8];
      #pragma unroll
      for (int j = 0; j < 8; j++){
        int i = g*8 + j + 1;                 // 1..72
        Hb[j] = *(const float2*)&hl[2*i + 2*(i>>2)];
      }
      __builtin_amdgcn_sched_group_barrier(0x100, 8, 0);  // cluster the 8 reads
      #pragma unroll
      for (int j = 0; j < 8; j++){
        int i = g*8 + j + 1;
        a0 = fmaf(Hb[j].x, c0.x, fmaf(Hb[j].y, c0.y, a0));
        a1 = fmaf(Hb[j].x, c1.x, fmaf(Hb[j].y, c1.y, a1));
        a2 = fmaf(Hb[j].x, c2.x, fmaf(Hb[j].y, c2.y, a2));
        a3 = fmaf(Hb[j].x, c3.x, fmaf(Hb[j].y, c3.y, a3));
        c3 = c2; c2 = c1; c1 = c0;
        if (i <= 68){   // new c0 = pair pr = 68-i; compile-time m0,m1
          float d0 = (float)(68 - 2*i) * sh;
          float d1 = (float)(67 - 2*i) * sh;
          c0 = make_float2(fexp2(k2c*d0*d0), fexp2(k2c*d1*d1));
        } else {
          c0 = make_float2(0.f, 0.f);        // pr < 0: zero pad
        }
      }
    }
    int o0 = 4*lane;
    // corr values in registers (IEEE-identical to the old table build)
    float xc0 = fmaf((float)(o0 - 1), 4.0f*stepFS, leftS);
    float xc1 = fmaf((float)(o0    ), 4.0f*stepFS, leftS);
    float xc2 = fmaf((float)(o0 + 1), 4.0f*stepFS, leftS);
    float xc3 = fmaf((float)(o0 + 2), 4.0f*stepFS, leftS);
    float cr0 = fexp2(k2c * xc0 * xc0);
    float cr1 = fexp2(k2c * xc1 * xc1);
    float cr2 = fexp2(k2c * xc2 * xc2);
    float cr3 = fexp2(k2c * xc3 * xc3);
    float4 stv = make_float4((a0 - padc*cr0)*rlen, (a1 - padc*cr1)*rlen,
                             (a2 - padc*cr2)*rlen, (a3 - padc*cr3)*rlen);
    *(float4*)&smem[e*256 + o0] = stv;
  }
  __syncthreads();   // #1 (of 2): all envs' st complete
  // fine grid: thread tid handles t = 4*tid..4*tid+3 (all share cc = tid)
  float ps[6] = {0,0,0,0,0,0};
  if (tid < 250){
    float x[4][4];
    #pragma unroll
    for (int ee=0; ee<4; ee++){
      const float* st = &smem[ee*256 + tid];
      x[ee][0]=st[0]; x[ee][1]=st[1]; x[ee][2]=st[2]; x[ee][3]=st[3];
    }
    __builtin_amdgcn_sched_group_barrier(0x100, 16, 0);   // cluster the reads
    #pragma unroll
    for (int k=0; k<4; k++){
      float u = (float)k * 0.25f;
      float um1 = u - 1.0f, um2 = u - 2.0f, up1 = u + 1.0f;
      float w0 = -u * um1 * um2 * (1.0f/6.0f);
      float w1 = up1 * um1 * um2 * 0.5f;
      float w2 = -u * up1 * um2 * 0.5f;
      float w3 = u * up1 * um1 * (1.0f/6.0f);
      float rr[4];
      #pragma unroll
      for (int ee=0; ee<4; ee++)
        rr[ee] = w0*x[ee][0] + w1*x[ee][1] + w2*x[ee][2] + w3*x[ee][3];
      ps[0] += fabsf(rr[0]-rr[1]);
      ps[1] += fabsf(rr[0]-rr[2]);
      ps[2] += fabsf(rr[0]-rr[3]);
      ps[3] += fabsf(rr[1]-rr[2]);
      ps[4] += fabsf(rr[1]-rr[3]);
      ps[5] += fabsf(rr[2]-rr[3]);
    }
  }
  #pragma unroll
  for (int pr=0; pr<6; pr++){
    float v = ps[pr];
    #pragma unroll
    for (int d=32; d>=1; d>>=1) v += __shfl_xor(v, d, 64);
    if (lane == 0) smem[4320 + wave*6 + pr] = v;
  }
  __syncthreads();   // #2 (of 2): partials visible
  if (tid < 6)
    dpair[tid*1280 + b] = smem[4320+tid] + smem[4326+tid] + smem[4332+tid] + smem[4338+tid];
}

// finalize: scale, masked max over pairs, then max over L + mean over F
__global__ void k_fin(const float* __restrict__ dpair, const float* __restrict__ wsf,
                      const int* __restrict__ istrain, float* __restrict__ out){
  __shared__ float str[1280], ste[1280];
  __shared__ float s1[128], s2[128];
  int tid = threadIdx.x;   // 256 threads, 1 block
  float hscale = wsf[8];
  bool t0 = istrain[0]!=0, t1 = istrain[1]!=0, t2 = istrain[2]!=0, t3 = istrain[3]!=0;
  bool trn[6] = { t0&&t1, t0&&t2, t0&&t3, t1&&t2, t1&&t3, t2&&t3 };
  for (int idx = tid; idx < 1280; idx += 256){
    float tmax = -INFINITY, trmax = -INFINITY;
    #pragma unroll
    for (int pr=0;pr<6;pr++){
      float h = dpair[pr*1280 + idx] * hscale;
      tmax = fmaxf(tmax, h);
      if (trn[pr]) trmax = fmaxf(trmax, h);
    }
    out[idx]        = trmax;   // train_results
    out[1280 + idx] = tmax;    // test_results
    str[idx] = trmax; ste[idx] = tmax;
  }
  __syncthreads();
  if (tid < 128){
    float m1 = -INFINITY, m2 = -INFINITY;
    for (int l=0;l<L_;l++){
      m1 = fmaxf(m1, str[l*F_ + tid]);
      m2 = fmaxf(m2, ste[l*F_ + tid]);
    }
    s1[tid] = m1; s2[tid] = m2;
  }
  __syncthreads();
  for (int g=64; g>=1; g>>=1){
    if (tid < g){ s1[tid] += s1[tid+g]; s2[tid] += s2[tid+g]; }
    __syncthreads();
  }
  if (tid == 0){
    out[2560] = s1[0] * (1.0f/128.0f);
    out[2561] = s2[0] * (1.0f/128.0f);
  }
}

extern "C" void kernel_launch(void* const* d_in, const int* in_sizes, int n_in,
                              void* d_out, int out_size, void* d_ws, size_t ws_size,
                              hipStream_t stream){
  const float* mat = (const float*)d_in[0];
  const float* par = (const float*)d_in[1];
  const int*  dlen = (const int*)d_in[2];
  const int*  istr = (const int*)d_in[3];
  float* out   = (float*)d_out;
  float* wsf   = (float*)d_ws;
  float* dpair = wsf + 12816;
  float* projT = wsf + 20496;

  // host-computable constants (bw's data-dependent factor is identically 1)
  double bw_d   = 1.06 * pow(512.0, -0.2);
  float  bw     = (float)bw_d;
  float  offset = expf(-0.5f / (bw*bw));
  float  k2c    = (float)(log((double)offset) * 1.4426950408889634);  // log2(offset)
  float  divisor = sqrtf(6.283185307179586f) * bw;

  k_pre <<<1320, 256, 0, stream>>>(mat, par, projT, wsf);
  k_red <<<1,   1024, 0, stream>>>(wsf, divisor);
  k_kde <<<1280, 256, 0, stream>>>(projT, dlen, wsf, dpair, k2c);
  k_fin <<<1,    256, 0, stream>>>(dpair, wsf, istr, out);
}